// Round 16
// baseline (176.014 us; speedup 1.0000x reference)
//
#include <hip/hip_runtime.h>
#include <hip/hip_bf16.h>

typedef __bf16 bf16_t;
typedef __attribute__((ext_vector_type(8))) __bf16 bf16x8;
typedef __attribute__((ext_vector_type(4))) float f32x4;
typedef __attribute__((ext_vector_type(16))) float f32x16;

// dims: B=8 S=1024 D=1024 H=16 hd=64
#define QSCALE 0.18033688011112042f   // (1/sqrt(64)) * log2(e)
#define RESCALE_THR 11.5f             // defer-max threshold in log2 units (~8 nats)

// ws layout (bytes). Ob aliases Xb (Xb dead after gemm_qkv).
#define OFF_XB      ((size_t)0)                       // bf16 [8192][1024]  16.78MB
#define OFF_WQKVT   ((size_t)16777216)                // bf16 [3072][1024]   6.29MB
#define OFF_WPROJT  ((size_t)(16777216 + 6291456))    // bf16 [1024][1024]   2.10MB
#define OFF_Q       ((size_t)(16777216 + 6291456 + 2097152)) // bf16 [128][1024][64]
#define OFF_K       (OFF_Q + (size_t)16777216)
#define OFF_V       (OFF_K + (size_t)16777216)        // transposed: [128][64][1024]
#define OFF_O       OFF_XB                            // bf16 [8192][1024] (alias)

typedef const __attribute__((address_space(1))) void* as1cv;
typedef __attribute__((address_space(3))) void* as3v;

__device__ __forceinline__ void load_lds16(const void* g, void* l) {
  __builtin_amdgcn_global_load_lds((as1cv)g, (as3v)l, 16, 0, 0);
}

__device__ __forceinline__ f32x4 mfma16(bf16x8 a, bf16x8 b, f32x4 c) {
  return __builtin_amdgcn_mfma_f32_16x16x32_bf16(a, b, c, 0, 0, 0);
}
__device__ __forceinline__ f32x16 mfma32(bf16x8 a, bf16x8 b, f32x16 c) {
  return __builtin_amdgcn_mfma_f32_32x32x16_bf16(a, b, c, 0, 0, 0);
}

__device__ __forceinline__ float fexp2(float x) { return __builtin_amdgcn_exp2f(x); }

// pack two f32 -> one u32 of two bf16 (compiler fuses to v_cvt_pk_bf16_f32; m240)
__device__ __forceinline__ unsigned pack2bf(float a, float b) {
  union { bf16_t h[2]; unsigned u; } x;
  x.h[0] = (bf16_t)a; x.h[1] = (bf16_t)b;
  return x.u;
}

__device__ __forceinline__ bf16x8 frag_from_words(unsigned w0, unsigned w1,
                                                  unsigned w2, unsigned w3) {
  union { unsigned u[4]; bf16x8 v; } x;
  x.u[0] = w0; x.u[1] = w1; x.u[2] = w2; x.u[3] = w3;
  return x.v;
}

// swizzled LDS read: 16B at (row, slotbyte) with XOR-(row&7) slot swizzle
__device__ __forceinline__ bf16x8 ldsr(const bf16_t* lds, int row, int slotbyte) {
  return *(const bf16x8*)((const char*)lds + row * 128 +
                          (slotbyte ^ ((row & 7) << 4)));
}

// ---------------- merged prologue: x->bf16 copy + both weight transposes ----------------
__global__ __launch_bounds__(256) void prologue_kernel(
    const float* __restrict__ x, bf16_t* __restrict__ Xb,
    const float* __restrict__ W1, bf16_t* __restrict__ Wt1,
    const float* __restrict__ W2, bf16_t* __restrict__ Wt2) {
  const int bid = blockIdx.x;
  if (bid < 4096) {
    const int i = bid * 256 + threadIdx.x;          // < 1048576
    const float4* p = (const float4*)x + (size_t)i * 2;
    float4 a = p[0], b = p[1];
    bf16x8 o;
    o[0] = (bf16_t)a.x; o[1] = (bf16_t)a.y; o[2] = (bf16_t)a.z; o[3] = (bf16_t)a.w;
    o[4] = (bf16_t)b.x; o[5] = (bf16_t)b.y; o[6] = (bf16_t)b.z; o[7] = (bf16_t)b.w;
    ((bf16x8*)Xb)[i] = o;
    return;
  }
  __shared__ float t[32][33];
  const int bx = (bid - 4096) & 127;                // 0..127 column-tile
  const int by = (bid - 4096) >> 7;                 // 0..31  row-tile
  const float* W;  bf16_t* Wt;  int cols, c0;
  if (bx < 96) { W = W1; Wt = Wt1; cols = 3072; c0 = bx * 32; }
  else         { W = W2; Wt = Wt2; cols = 1024; c0 = (bx - 96) * 32; }
  const int r0 = by * 32;
  const int tx = threadIdx.x & 31, ty = threadIdx.x >> 5;
  for (int rr = ty; rr < 32; rr += 8)
    t[rr][tx] = W[(size_t)(r0 + rr) * cols + c0 + tx];
  __syncthreads();
  for (int rr = ty; rr < 32; rr += 8)
    Wt[(size_t)(c0 + rr) * 1024 + r0 + tx] = (bf16_t)t[tx][rr];
}

// ---------------- GEMM mainloop: 128x128 tile, BK=64, *** 2 waves *** ----------------
// Wave w owns rows [w*64, w*64+64) x all 128 cols (wave tile 64x128). LDS read
// traffic per block-step drops 64KB -> 48KB (A read ONCE; only B duplicated) —
// the R15 analysis put LDS-read BW (~85 B/cy, m134) as the largest un-attacked
// serial term. Per-wave MFMA cluster doubles to 64 (better cover for the R14
// same-buffer prefetch, kept verbatim). acc[4][8] = 128 VGPR; live ~250.
// Race ledger identical to R14: lgkm0+barrier before STAGE; vmcnt0+barrier
// at step top; sched_barrier pins MFMA between stage-issue and vmcnt.

__device__ __forceinline__ void gemm_mainloop_w2(
    const bf16_t* __restrict__ A, const bf16_t* __restrict__ Bt,
    int m0, int n0, bf16_t* Alds, bf16_t* Blds, f32x4 acc[4][8]) {
  const int tid = threadIdx.x;            // 0..127 (2 waves)
  const int w = tid >> 6, lane = tid & 63;
  const int lr = lane & 15, lg = lane >> 4;
#pragma unroll
  for (int m = 0; m < 4; ++m)
#pragma unroll
    for (int n = 0; n < 8; ++n)
      acc[m][n] = f32x4{0.f, 0.f, 0.f, 0.f};

  const int crow = lane >> 3;                    // 0..7 row within 8-row chunk
  const int cels = (((lane & 7) ^ crow) * 8);    // pre-swizzled source slot
  const int rx = (lr & 7) << 4;                  // fragment-read XOR key

  // 32 chunks (16 A + 16 B) of 1KB; wave w loads chunks [w*8, w*8+8) of each.
#define STAGE_AB(kt_)                                                            \
  do {                                                                           \
    _Pragma("unroll")                                                            \
    for (int it = 0; it < 8; ++it) {                                             \
      const int c = w * 8 + it;                /* chunk 0..15, uniform/wave */   \
      const int rA = c * 8 + crow;             /* tile row 0..127 */             \
      load_lds16(A + (size_t)(m0 + rA) * 1024 + (kt_) * 64 + cels,               \
                 (char*)Alds + c * 1024);                                        \
      load_lds16(Bt + (size_t)(n0 + rA) * 1024 + (kt_) * 64 + cels,              \
                 (char*)Blds + c * 1024);                                        \
    }                                                                            \
  } while (0)

  STAGE_AB(0);

  for (int kt = 0; kt < 16; ++kt) {
    asm volatile("s_waitcnt vmcnt(0)" ::: "memory");   // my stage landed
    asm volatile("s_barrier" ::: "memory");            // everyone's landed

    bf16x8 af[4][2], bfr[8][2];
#pragma unroll
    for (int m = 0; m < 4; ++m)
#pragma unroll
      for (int kk = 0; kk < 2; ++kk)
        af[m][kk] = ldsr(Alds, w * 64 + m * 16 + lr, kk * 64 + lg * 16);
#pragma unroll
    for (int n = 0; n < 8; ++n)
#pragma unroll
      for (int kk = 0; kk < 2; ++kk)
        bfr[n][kk] = ldsr(Blds, n * 16 + lr, kk * 64 + lg * 16);
    asm volatile("s_waitcnt lgkmcnt(0)" ::: "memory"); // my reads complete
    __builtin_amdgcn_sched_barrier(0);
    asm volatile("s_barrier" ::: "memory");            // all reads done: LDS dead

    if (kt + 1 < 16) STAGE_AB(kt + 1);                 // prefetch into SAME buffer

    __builtin_amdgcn_s_setprio(1);
#pragma unroll
    for (int kk = 0; kk < 2; ++kk)
#pragma unroll
      for (int m = 0; m < 4; ++m)
#pragma unroll
        for (int n = 0; n < 8; ++n)
          acc[m][n] = mfma16(af[m][kk], bfr[n][kk], acc[m][n]);
    __builtin_amdgcn_s_setprio(0);
    __builtin_amdgcn_sched_barrier(0);                 // MFMA stays before vmcnt
  }
#undef STAGE_AB
}

// XCD-chunked remap (T1): bijective, grid = 8 * MT_PER * NT.
__device__ __forceinline__ void xcd_remap(int bid, int MT_PER, int* mt, int* nt) {
  const int r = bid & 7, q = bid >> 3;
  *mt = r * MT_PER + (q & (MT_PER - 1));
  *nt = q / MT_PER;
}

// ---------------- GEMM1: X @ Wqkv^T -> scatter Q(scaled)/K/V(transposed) bf16 ----------------

__global__ __launch_bounds__(128) void gemm_qkv(
    const bf16_t* __restrict__ A, const bf16_t* __restrict__ Bt,
    const float* __restrict__ bias,
    bf16_t* __restrict__ Qh, bf16_t* __restrict__ Kh, bf16_t* __restrict__ Vt) {
  __shared__ alignas(128) bf16_t Alds[128 * 64];
  __shared__ alignas(128) bf16_t Blds[128 * 64];
  int mt, nt;
  xcd_remap(blockIdx.x, 8, &mt, &nt);       // 64 m-tiles, 24 n-tiles
  const int m0 = mt * 128, n0 = nt * 128;
  f32x4 acc[4][8];
  gemm_mainloop_w2(A, Bt, m0, n0, Alds, Blds, acc);

  const int tid = threadIdx.x, w = tid >> 6, lane = tid & 63;
  const int lr = lane & 15, lg = lane >> 4;
  const int section = n0 >> 10;  // 0=Q 1=K 2=V (uniform per block)
#pragma unroll
  for (int n = 0; n < 8; ++n) {
    const int c = n0 + n * 16 + lr;             // global col in [0,3072)
    const float bi = bias[c];
    const int d1024 = c & 1023;
    const int h = d1024 >> 6, d = d1024 & 63;
#pragma unroll
    for (int m = 0; m < 4; ++m) {
#pragma unroll
      for (int j = 0; j < 4; ++j) {
        const int r = m0 + w * 64 + m * 16 + lg * 4 + j;  // token index
        const int b = r >> 10, s = r & 1023;
        const size_t hb = ((size_t)(b * 16 + h)) << 16;
        const float v = acc[m][n][j] + bi;
        if (section == 0)      Qh[hb + (size_t)s * 64 + d] = (bf16_t)(v * QSCALE);
        else if (section == 1) Kh[hb + (size_t)s * 64 + d] = (bf16_t)v;
        else                   Vt[hb + (size_t)d * 1024 + s] = (bf16_t)v;
      }
    }
  }
}

// ---------------- GEMM2: O @ Wproj^T + b -> fp32 out ----------------

__global__ __launch_bounds__(128) void gemm_out(
    const bf16_t* __restrict__ A, const bf16_t* __restrict__ Bt,
    const float* __restrict__ bias, float* __restrict__ out) {
  __shared__ alignas(128) bf16_t Alds[128 * 64];
  __shared__ alignas(128) bf16_t Blds[128 * 64];
  int mt, nt;
  xcd_remap(blockIdx.x, 8, &mt, &nt);       // 64 m-tiles, 8 n-tiles
  const int m0 = mt * 128, n0 = nt * 128;
  f32x4 acc[4][8];
  gemm_mainloop_w2(A, Bt, m0, n0, Alds, Blds, acc);

  const int tid = threadIdx.x, w = tid >> 6, lane = tid & 63;
  const int lr = lane & 15, lg = lane >> 4;
#pragma unroll
  for (int n = 0; n < 8; ++n) {
    const int c = n0 + n * 16 + lr;
    const float bi = bias[c];
#pragma unroll
    for (int m = 0; m < 4; ++m)
#pragma unroll
      for (int j = 0; j < 4; ++j) {
        const int r = m0 + w * 64 + m * 16 + lg * 4 + j;
        out[(size_t)r * 1024 + c] = acc[m][n][j] + bi;
      }
  }
}

// ---------------- flash attention, swapped-operand (m214/T12 structure) ----------------

__global__ __launch_bounds__(256, 4) void attn_kernel(
    const bf16_t* __restrict__ Qh, const bf16_t* __restrict__ Kh,
    const bf16_t* __restrict__ Vt, bf16_t* __restrict__ Ob) {
  __shared__ alignas(128) bf16_t Klds[2][64 * 64];  // [kv][d], XOR-swizzled slots
  __shared__ alignas(128) bf16_t Vlds[2][64 * 64];  // [d][kv], XOR-swizzled slots

  const int x = blockIdx.x;                // 0..1023
  const int bh = ((x & 7) << 4) | (x >> 6);
  const int qt = (x >> 3) & 7;
  const int b = bh >> 4, h = bh & 15;
  const int tid = threadIdx.x, w = tid >> 6, lane = tid & 63;
  const int q31 = lane & 31, hi = lane >> 5;
  const size_t base = (size_t)bh << 16;    // 65536 elements per head

  const int qrow0 = qt * 128 + w * 32;

  bf16x8 qf[4];
#pragma unroll
  for (int c = 0; c < 4; ++c)
    qf[c] = *(const bf16x8*)(Qh + base + (size_t)(qrow0 + q31) * 64 + hi * 8 + 16 * c);

  f32x16 oacc0, oacc1;
#pragma unroll
  for (int r = 0; r < 16; ++r) { oacc0[r] = 0.f; oacc1[r] = 0.f; }
  float mreg = -1e30f, lreg = 0.f;

  const int srow = lane >> 3;
  const int sslot = (((lane & 7) ^ srow) << 3);

#define STAGE_KV(bsel, kt_)                                                        \
  do {                                                                             \
    _Pragma("unroll")                                                              \
    for (int it = 0; it < 2; ++it) {                                               \
      const int c = it * 4 + w;                                                    \
      const int r = c * 8 + srow;                                                  \
      load_lds16(Kh + base + (size_t)((kt_) * 64 + r) * 64 + sslot,                \
                 (char*)&Klds[bsel][0] + c * 1024);                                \
      load_lds16(Vt + base + (size_t)r * 1024 + (kt_) * 64 + sslot,                \
                 (char*)&Vlds[bsel][0] + c * 1024);                                \
    }                                                                              \
  } while (0)

  STAGE_KV(0, 0);
  asm volatile("s_waitcnt vmcnt(0)" ::: "memory");
  __syncthreads();
  int cur = 0;

  for (int kt = 0; kt < 16; ++kt) {
    if (kt + 1 < 16) STAGE_KV(cur ^ 1, kt + 1);

    const bf16_t* Kb = &Klds[cur][0];
    const bf16_t* Vb = &Vlds[cur][0];

    f32x16 st0, st1;
#pragma unroll
    for (int r = 0; r < 16; ++r) { st0[r] = 0.f; st1[r] = 0.f; }
#pragma unroll
    for (int c = 0; c < 4; ++c) {
      const int sb = hi * 16 + 32 * c;
      bf16x8 k0 = ldsr(Kb, q31, sb);
      bf16x8 k1 = ldsr(Kb, 32 + q31, sb);
      __builtin_amdgcn_s_setprio(1);
      st0 = mfma32(k0, qf[c], st0);
      st1 = mfma32(k1, qf[c], st1);
      __builtin_amdgcn_s_setprio(0);
    }

    float mx[8];
#pragma unroll
    for (int r = 0; r < 8; ++r)
      mx[r] = fmaxf(fmaxf(st0[r], st0[r + 8]), fmaxf(st1[r], st1[r + 8]));
#pragma unroll
    for (int r = 0; r < 4; ++r) mx[r] = fmaxf(mx[r], mx[r + 4]);
    float tm = fmaxf(fmaxf(mx[0], mx[1]), fmaxf(mx[2], mx[3]));
    tm = fmaxf(tm, __shfl_xor(tm, 32));

    if (!__all(tm - mreg <= RESCALE_THR)) {
      const float mnew = fmaxf(mreg, tm);
      const float corr = fexp2(mreg - mnew);
      lreg *= corr;
#pragma unroll
      for (int r = 0; r < 16; ++r) { oacc0[r] *= corr; oacc1[r] *= corr; }
      mreg = mnew;
    }

    bf16x8 pa[4];
    float psum = 0.f;
#define GROUP(KC, STV, BASE)                                                   \
    {                                                                          \
      const float e0 = fexp2(STV[BASE + 0] - mreg);                            \
      const float e1 = fexp2(STV[BASE + 1] - mreg);                            \
      const float e2 = fexp2(STV[BASE + 2] - mreg);                            \
      const float e3 = fexp2(STV[BASE + 3] - mreg);                            \
      const float e4 = fexp2(STV[BASE + 4] - mreg);                            \
      const float e5 = fexp2(STV[BASE + 5] - mreg);                            \
      const float e6 = fexp2(STV[BASE + 6] - mreg);                            \
      const float e7 = fexp2(STV[BASE + 7] - mreg);                            \
      psum += ((e0 + e1) + (e2 + e3)) + ((e4 + e5) + (e6 + e7));               \
      unsigned wa = pack2bf(e0, e1), wb = pack2bf(e4, e5);                     \
      asm volatile("v_permlane32_swap_b32 %0, %1" : "+v"(wa), "+v"(wb));       \
      unsigned wc = pack2bf(e2, e3), wd = pack2bf(e6, e7);                     \
      asm volatile("v_permlane32_swap_b32 %0, %1" : "+v"(wc), "+v"(wd));       \
      pa[KC] = frag_from_words(wa, wc, wb, wd);                                \
    }
    GROUP(0, st0, 0)
    GROUP(1, st0, 8)
    GROUP(2, st1, 0)
    GROUP(3, st1, 8)
#undef GROUP
    lreg += psum + __shfl_xor(psum, 32);

#pragma unroll
    for (int kc = 0; kc < 4; ++kc) {
      const int sb = hi * 16 + 32 * kc;
      bf16x8 v0 = ldsr(Vb, q31, sb);
      bf16x8 v1 = ldsr(Vb, 32 + q31, sb);
      __builtin_amdgcn_s_setprio(1);
      oacc0 = mfma32(v0, pa[kc], oacc0);
      oacc1 = mfma32(v1, pa[kc], oacc1);
      __builtin_amdgcn_s_setprio(0);
    }

    asm volatile("s_waitcnt vmcnt(0)" ::: "memory");
    __syncthreads();
    cur ^= 1;
  }
#undef STAGE_KV

  const float inv = 1.0f / lreg;
  const int s_tok = qrow0 + q31;
  bf16_t* obase = Ob + (size_t)(b * 1024 + s_tok) * 1024 + h * 64;
#pragma unroll
  for (int i = 0; i < 8; ++i) {
    const int dbase = ((2 * i) & 3) + 8 * ((2 * i) >> 2) + 4 * hi;
    *(unsigned*)(obase + dbase) =
        pack2bf(oacc0[2 * i] * inv, oacc0[2 * i + 1] * inv);
    *(unsigned*)(obase + 32 + dbase) =
        pack2bf(oacc1[2 * i] * inv, oacc1[2 * i + 1] * inv);
  }
}

// ---------------- launch ----------------

extern "C" void kernel_launch(void* const* d_in, const int* in_sizes, int n_in,
                              void* d_out, int out_size, void* d_ws, size_t ws_size,
                              hipStream_t stream) {
  const float* x     = (const float*)d_in[0];
  const float* Wqkv  = (const float*)d_in[1];
  const float* bqkv  = (const float*)d_in[2];
  const float* Wproj = (const float*)d_in[3];
  const float* bproj = (const float*)d_in[4];
  float* out = (float*)d_out;
  char* ws = (char*)d_ws;

  bf16_t* Xb  = (bf16_t*)(ws + OFF_XB);
  bf16_t* Wqt = (bf16_t*)(ws + OFF_WQKVT);
  bf16_t* Wpt = (bf16_t*)(ws + OFF_WPROJT);
  bf16_t* Qh  = (bf16_t*)(ws + OFF_Q);
  bf16_t* Kh  = (bf16_t*)(ws + OFF_K);
  bf16_t* Vt  = (bf16_t*)(ws + OFF_V);
  bf16_t* Ob  = (bf16_t*)(ws + OFF_O);  // aliases Xb (dead after gemm_qkv)

  prologue_kernel<<<8192, 256, 0, stream>>>(x, Xb, Wqkv, Wqt, Wproj, Wpt);
  gemm_qkv<<<1536, 128, 0, stream>>>(Xb, Wqt, bqkv, Qh, Kh, Vt);   // 8 XCD x 8 mt x 24 nt
  attn_kernel<<<1024, 256, 0, stream>>>(Qh, Kh, Vt, Ob);
  gemm_out<<<512, 128, 0, stream>>>(Ob, Wpt, bproj, out);          // 8 XCD x 8 mt x 8 nt
}

// Round 17
// 168.480 us; speedup vs baseline: 1.0447x; 1.0447x over previous
//
#include <hip/hip_runtime.h>
#include <hip/hip_bf16.h>

typedef __bf16 bf16_t;
typedef __attribute__((ext_vector_type(8))) __bf16 bf16x8;
typedef __attribute__((ext_vector_type(4))) float f32x4;
typedef __attribute__((ext_vector_type(16))) float f32x16;

// dims: B=8 S=1024 D=1024 H=16 hd=64
#define QSCALE 0.18033688011112042f   // (1/sqrt(64)) * log2(e)
#define RESCALE_THR 11.5f             // defer-max threshold in log2 units (~8 nats)

// ws layout (bytes). Ob aliases Xb (Xb dead after gemm_qkv).
#define OFF_XB      ((size_t)0)                       // bf16 [8192][1024]  16.78MB
#define OFF_WQKVT   ((size_t)16777216)                // bf16 [3072][1024]   6.29MB
#define OFF_WPROJT  ((size_t)(16777216 + 6291456))    // bf16 [1024][1024]   2.10MB
#define OFF_Q       ((size_t)(16777216 + 6291456 + 2097152)) // bf16 [128][1024][64]
#define OFF_K       (OFF_Q + (size_t)16777216)
#define OFF_V       (OFF_K + (size_t)16777216)        // transposed: [128][64][1024]
#define OFF_O       OFF_XB                            // bf16 [8192][1024] (alias)

typedef const __attribute__((address_space(1))) void* as1cv;
typedef __attribute__((address_space(3))) void* as3v;

__device__ __forceinline__ void load_lds16(const void* g, void* l) {
  __builtin_amdgcn_global_load_lds((as1cv)g, (as3v)l, 16, 0, 0);
}

__device__ __forceinline__ f32x4 mfma16(bf16x8 a, bf16x8 b, f32x4 c) {
  return __builtin_amdgcn_mfma_f32_16x16x32_bf16(a, b, c, 0, 0, 0);
}
__device__ __forceinline__ f32x16 mfma32(bf16x8 a, bf16x8 b, f32x16 c) {
  return __builtin_amdgcn_mfma_f32_32x32x16_bf16(a, b, c, 0, 0, 0);
}

__device__ __forceinline__ float fexp2(float x) { return __builtin_amdgcn_exp2f(x); }

// pack two f32 -> one u32 of two bf16 (compiler fuses to v_cvt_pk_bf16_f32; m240)
__device__ __forceinline__ unsigned pack2bf(float a, float b) {
  union { bf16_t h[2]; unsigned u; } x;
  x.h[0] = (bf16_t)a; x.h[1] = (bf16_t)b;
  return x.u;
}

__device__ __forceinline__ bf16x8 frag_from_words(unsigned w0, unsigned w1,
                                                  unsigned w2, unsigned w3) {
  union { unsigned u[4]; bf16x8 v; } x;
  x.u[0] = w0; x.u[1] = w1; x.u[2] = w2; x.u[3] = w3;
  return x.v;
}

// swizzled LDS read: 16B at (row, slotbyte) with XOR-(row&7) slot swizzle
__device__ __forceinline__ bf16x8 ldsr(const bf16_t* lds, int row, int slotbyte) {
  return *(const bf16x8*)((const char*)lds + row * 128 +
                          (slotbyte ^ ((row & 7) << 4)));
}

// ---------------- merged prologue: x->bf16 copy + both weight transposes ----------------
// blocks [0,4096): cvt of x (8 bf16/thread). blocks [4096,8192): 32x32 transpose
// tiles; tx<96 of each y-row -> Wqkv (cols 3072), else Wproj (cols 1024).
__global__ __launch_bounds__(256) void prologue_kernel(
    const float* __restrict__ x, bf16_t* __restrict__ Xb,
    const float* __restrict__ W1, bf16_t* __restrict__ Wt1,
    const float* __restrict__ W2, bf16_t* __restrict__ Wt2) {
  const int bid = blockIdx.x;
  if (bid < 4096) {
    const int i = bid * 256 + threadIdx.x;          // < 1048576
    const float4* p = (const float4*)x + (size_t)i * 2;
    float4 a = p[0], b = p[1];
    bf16x8 o;
    o[0] = (bf16_t)a.x; o[1] = (bf16_t)a.y; o[2] = (bf16_t)a.z; o[3] = (bf16_t)a.w;
    o[4] = (bf16_t)b.x; o[5] = (bf16_t)b.y; o[6] = (bf16_t)b.z; o[7] = (bf16_t)b.w;
    ((bf16x8*)Xb)[i] = o;
    return;
  }
  __shared__ float t[32][33];
  const int bx = (bid - 4096) & 127;                // 0..127 column-tile
  const int by = (bid - 4096) >> 7;                 // 0..31  row-tile
  const float* W;  bf16_t* Wt;  int cols, c0;
  if (bx < 96) { W = W1; Wt = Wt1; cols = 3072; c0 = bx * 32; }
  else         { W = W2; Wt = Wt2; cols = 1024; c0 = (bx - 96) * 32; }
  const int r0 = by * 32;
  const int tx = threadIdx.x & 31, ty = threadIdx.x >> 5;
  for (int rr = ty; rr < 32; rr += 8)
    t[rr][tx] = W[(size_t)(r0 + rr) * cols + c0 + tx];
  __syncthreads();
  for (int rr = ty; rr < 32; rr += 8)
    Wt[(size_t)(c0 + rr) * 1024 + r0 + tx] = (bf16_t)t[tx][rr];
}

// ---------------- GEMM mainloop (128x128 tile, BK=64, K=1024) ----------------
// R5/R11 structure + SAME-BUFFER prefetch overlap (R14 win: 105->88 us): after
// the fragment ds_reads complete (lgkm0 + barrier), the LDS tile is dead
// (frags in registers), so the NEXT step's global_load_lds go into the same
// buffer and their latency is covered by this step's 32-MFMA cluster — with
// zero extra LDS (occupancy preserved; why R6/R7's dbuf variants lost, and
// why R16's 2-wave variant lost: every trade that pays with occupancy loses).
// Race ledger: barrier#2 preceded by every wave's lgkmcnt(0) -> all reads done
// before any stage data lands; next iter's vmcnt(0)+barrier#1 -> all stages
// landed before reads. sched_barrier(0) pins MFMA between stage-issue & vmcnt.

__device__ __forceinline__ void gemm_mainloop_1024(
    const bf16_t* __restrict__ A, const bf16_t* __restrict__ Bt,
    int m0, int n0, bf16_t* Alds, bf16_t* Blds, f32x4 acc[4][4]) {
  const int tid = threadIdx.x;
  const int w = tid >> 6, lane = tid & 63;
  const int wr = w >> 1, wc = w & 1;
  const int lr = lane & 15, lg = lane >> 4;
#pragma unroll
  for (int m = 0; m < 4; ++m)
#pragma unroll
    for (int n = 0; n < 4; ++n)
      acc[m][n] = f32x4{0.f, 0.f, 0.f, 0.f};

  const int crow = lane >> 3;                    // 0..7 row within 8-row chunk
  const int cels = (((lane & 7) ^ crow) * 8);    // pre-swizzled source slot
  const int rx = (lr & 7) << 4;                  // fragment-read XOR key

#define STAGE_AB(kt_)                                                            \
  do {                                                                           \
    _Pragma("unroll")                                                            \
    for (int it = 0; it < 4; ++it) {                                             \
      const int c = it * 4 + w;                /* chunk 0..15, uniform/wave */   \
      const int rA = c * 8 + crow;             /* tile row 0..127 */             \
      load_lds16(A + (size_t)(m0 + rA) * 1024 + (kt_) * 64 + cels,               \
                 (char*)Alds + c * 1024);                                        \
      load_lds16(Bt + (size_t)(n0 + rA) * 1024 + (kt_) * 64 + cels,              \
                 (char*)Blds + c * 1024);                                        \
    }                                                                            \
  } while (0)

  STAGE_AB(0);

  for (int kt = 0; kt < 16; ++kt) {
    asm volatile("s_waitcnt vmcnt(0)" ::: "memory");   // my stage landed
    asm volatile("s_barrier" ::: "memory");            // everyone's landed

    bf16x8 af[4][2], bfr[4][2];
#pragma unroll
    for (int m = 0; m < 4; ++m)
#pragma unroll
      for (int kk = 0; kk < 2; ++kk)
        af[m][kk] = *(const bf16x8*)((const char*)Alds + (wr * 64 + m * 16 + lr) * 128 +
                                     ((kk * 64 + lg * 16) ^ rx));
#pragma unroll
    for (int n = 0; n < 4; ++n)
#pragma unroll
      for (int kk = 0; kk < 2; ++kk)
        bfr[n][kk] = *(const bf16x8*)((const char*)Blds + (wc * 64 + n * 16 + lr) * 128 +
                                      ((kk * 64 + lg * 16) ^ rx));
    asm volatile("s_waitcnt lgkmcnt(0)" ::: "memory"); // my reads complete
    __builtin_amdgcn_sched_barrier(0);
    asm volatile("s_barrier" ::: "memory");            // all reads done: LDS dead

    if (kt + 1 < 16) STAGE_AB(kt + 1);                 // prefetch into SAME buffer

    __builtin_amdgcn_s_setprio(1);
#pragma unroll
    for (int kk = 0; kk < 2; ++kk)
#pragma unroll
      for (int m = 0; m < 4; ++m)
#pragma unroll
        for (int n = 0; n < 4; ++n)
          acc[m][n] = mfma16(af[m][kk], bfr[n][kk], acc[m][n]);
    __builtin_amdgcn_s_setprio(0);
    __builtin_amdgcn_sched_barrier(0);                 // MFMA stays before vmcnt
  }
#undef STAGE_AB
}

// XCD-chunked remap (T1): hardware assigns XCD = bid % 8; give XCD r the
// contiguous m-tile range [r*MT_PER, (r+1)*MT_PER), nt-outer/mt-inner, so each
// XCD's A panels (MT_PER x 256 KB = 2 MB) stay L2-resident across the n sweep
// and the 8 concurrent mt-blocks share one B panel. Bijective: grid = 8*MT_PER*NT.
__device__ __forceinline__ void xcd_remap(int bid, int MT_PER, int* mt, int* nt) {
  const int r = bid & 7, q = bid >> 3;
  *mt = r * MT_PER + (q & (MT_PER - 1));
  *nt = q / MT_PER;
}

// ---------------- GEMM1: X @ Wqkv^T -> scatter Q(scaled)/K/V(transposed) bf16 ----------------

__global__ __launch_bounds__(256) void gemm_qkv(
    const bf16_t* __restrict__ A, const bf16_t* __restrict__ Bt,
    const float* __restrict__ bias,
    bf16_t* __restrict__ Qh, bf16_t* __restrict__ Kh, bf16_t* __restrict__ Vt) {
  __shared__ alignas(128) bf16_t Alds[128 * 64];
  __shared__ alignas(128) bf16_t Blds[128 * 64];
  int mt, nt;
  xcd_remap(blockIdx.x, 8, &mt, &nt);       // 64 m-tiles, 24 n-tiles
  const int m0 = mt * 128, n0 = nt * 128;
  f32x4 acc[4][4];
  gemm_mainloop_1024(A, Bt, m0, n0, Alds, Blds, acc);

  const int tid = threadIdx.x, w = tid >> 6, lane = tid & 63;
  const int wr = w >> 1, wc = w & 1, lr = lane & 15, lg = lane >> 4;
  const int section = n0 >> 10;  // 0=Q 1=K 2=V (uniform per block)
#pragma unroll
  for (int n = 0; n < 4; ++n) {
    const int c = n0 + wc * 64 + n * 16 + lr;   // global col in [0,3072)
    const float bi = bias[c];
    const int d1024 = c & 1023;
    const int h = d1024 >> 6, d = d1024 & 63;
#pragma unroll
    for (int m = 0; m < 4; ++m) {
#pragma unroll
      for (int j = 0; j < 4; ++j) {
        const int r = m0 + wr * 64 + m * 16 + lg * 4 + j;  // token index
        const int b = r >> 10, s = r & 1023;
        const size_t hb = ((size_t)(b * 16 + h)) << 16;
        const float v = acc[m][n][j] + bi;
        if (section == 0)      Qh[hb + (size_t)s * 64 + d] = (bf16_t)(v * QSCALE);
        else if (section == 1) Kh[hb + (size_t)s * 64 + d] = (bf16_t)v;
        else                   Vt[hb + (size_t)d * 1024 + s] = (bf16_t)v;
      }
    }
  }
}

// ---------------- GEMM2: O @ Wproj^T + b -> fp32 out ----------------

__global__ __launch_bounds__(256) void gemm_out(
    const bf16_t* __restrict__ A, const bf16_t* __restrict__ Bt,
    const float* __restrict__ bias, float* __restrict__ out) {
  __shared__ alignas(128) bf16_t Alds[128 * 64];
  __shared__ alignas(128) bf16_t Blds[128 * 64];
  int mt, nt;
  xcd_remap(blockIdx.x, 8, &mt, &nt);       // 64 m-tiles, 8 n-tiles
  const int m0 = mt * 128, n0 = nt * 128;
  f32x4 acc[4][4];
  gemm_mainloop_1024(A, Bt, m0, n0, Alds, Blds, acc);

  const int tid = threadIdx.x, w = tid >> 6, lane = tid & 63;
  const int wr = w >> 1, wc = w & 1, lr = lane & 15, lg = lane >> 4;
#pragma unroll
  for (int n = 0; n < 4; ++n) {
    const int c = n0 + wc * 64 + n * 16 + lr;
    const float bi = bias[c];
#pragma unroll
    for (int m = 0; m < 4; ++m)
#pragma unroll
      for (int j = 0; j < 4; ++j) {
        const int r = m0 + wr * 64 + m * 16 + lg * 4 + j;
        out[(size_t)r * 1024 + c] = acc[m][n][j] + bi;
      }
  }
}

// ---------------- flash attention, swapped-operand (m214/T12 structure) ----------------
// 4 waves x 32 q-rows. KVBLK=64, dbuf LDS. QK^T computed as St = K·Q^T so each
// lane owns one q-row (col = lane&31); softmax is in-register (tree + 1 shfl_xor(32)).
// P -> PV B-frags via pack2bf + v_permlane32_swap (no P LDS round-trip).
// PV computed as O^T = V^T·P^T so rescale corr is a per-lane scalar.

__global__ __launch_bounds__(256, 4) void attn_kernel(
    const bf16_t* __restrict__ Qh, const bf16_t* __restrict__ Kh,
    const bf16_t* __restrict__ Vt, bf16_t* __restrict__ Ob) {
  __shared__ alignas(128) bf16_t Klds[2][64 * 64];  // [kv][d], XOR-swizzled slots
  __shared__ alignas(128) bf16_t Vlds[2][64 * 64];  // [d][kv], XOR-swizzled slots

  // XCD-aware remap: all 8 q-tiles of one head land on one XCD (T1)
  const int x = blockIdx.x;                // 0..1023
  const int bh = ((x & 7) << 4) | (x >> 6);
  const int qt = (x >> 3) & 7;
  const int b = bh >> 4, h = bh & 15;
  const int tid = threadIdx.x, w = tid >> 6, lane = tid & 63;
  const int q31 = lane & 31, hi = lane >> 5;
  const size_t base = (size_t)bh << 16;    // 65536 elements per head

  const int qrow0 = qt * 128 + w * 32;

  // Q fragments (B-operand of swapped QK^T)
  bf16x8 qf[4];
#pragma unroll
  for (int c = 0; c < 4; ++c)
    qf[c] = *(const bf16x8*)(Qh + base + (size_t)(qrow0 + q31) * 64 + hi * 8 + 16 * c);

  f32x16 oacc0, oacc1;
#pragma unroll
  for (int r = 0; r < 16; ++r) { oacc0[r] = 0.f; oacc1[r] = 0.f; }
  float mreg = -1e30f, lreg = 0.f;

  const int srow = lane >> 3;
  const int sslot = (((lane & 7) ^ srow) << 3);

#define STAGE_KV(bsel, kt_)                                                        \
  do {                                                                             \
    _Pragma("unroll")                                                              \
    for (int it = 0; it < 2; ++it) {                                               \
      const int c = it * 4 + w;                                                    \
      const int r = c * 8 + srow;                                                  \
      load_lds16(Kh + base + (size_t)((kt_) * 64 + r) * 64 + sslot,                \
                 (char*)&Klds[bsel][0] + c * 1024);                                \
      load_lds16(Vt + base + (size_t)r * 1024 + (kt_) * 64 + sslot,                \
                 (char*)&Vlds[bsel][0] + c * 1024);                                \
    }                                                                              \
  } while (0)

  STAGE_KV(0, 0);
  asm volatile("s_waitcnt vmcnt(0)" ::: "memory");
  __syncthreads();
  int cur = 0;

  for (int kt = 0; kt < 16; ++kt) {
    if (kt + 1 < 16) STAGE_KV(cur ^ 1, kt + 1);

    const bf16_t* Kb = &Klds[cur][0];
    const bf16_t* Vb = &Vlds[cur][0];

    f32x16 st0, st1;
#pragma unroll
    for (int r = 0; r < 16; ++r) { st0[r] = 0.f; st1[r] = 0.f; }
#pragma unroll
    for (int c = 0; c < 4; ++c) {
      const int sb = hi * 16 + 32 * c;
      bf16x8 k0 = ldsr(Kb, q31, sb);
      bf16x8 k1 = ldsr(Kb, 32 + q31, sb);
      __builtin_amdgcn_s_setprio(1);
      st0 = mfma32(k0, qf[c], st0);
      st1 = mfma32(k1, qf[c], st1);
      __builtin_amdgcn_s_setprio(0);
    }

    float mx[8];
#pragma unroll
    for (int r = 0; r < 8; ++r)
      mx[r] = fmaxf(fmaxf(st0[r], st0[r + 8]), fmaxf(st1[r], st1[r + 8]));
#pragma unroll
    for (int r = 0; r < 4; ++r) mx[r] = fmaxf(mx[r], mx[r + 4]);
    float tm = fmaxf(fmaxf(mx[0], mx[1]), fmaxf(mx[2], mx[3]));
    tm = fmaxf(tm, __shfl_xor(tm, 32));

    if (!__all(tm - mreg <= RESCALE_THR)) {
      const float mnew = fmaxf(mreg, tm);
      const float corr = fexp2(mreg - mnew);
      lreg *= corr;
#pragma unroll
      for (int r = 0; r < 16; ++r) { oacc0[r] *= corr; oacc1[r] *= corr; }
      mreg = mnew;
    }

    bf16x8 pa[4];
    float psum = 0.f;
#define GROUP(KC, STV, BASE)                                                   \
    {                                                                          \
      const float e0 = fexp2(STV[BASE + 0] - mreg);                            \
      const float e1 = fexp2(STV[BASE + 1] - mreg);                            \
      const float e2 = fexp2(STV[BASE + 2] - mreg);                            \
      const float e3 = fexp2(STV[BASE + 3] - mreg);                            \
      const float e4 = fexp2(STV[BASE + 4] - mreg);                            \
      const float e5 = fexp2(STV[BASE + 5] - mreg);                            \
      const float e6 = fexp2(STV[BASE + 6] - mreg);                            \
      const float e7 = fexp2(STV[BASE + 7] - mreg);                            \
      psum += ((e0 + e1) + (e2 + e3)) + ((e4 + e5) + (e6 + e7));               \
      unsigned wa = pack2bf(e0, e1), wb = pack2bf(e4, e5);                     \
      asm volatile("v_permlane32_swap_b32 %0, %1" : "+v"(wa), "+v"(wb));       \
      unsigned wc = pack2bf(e2, e3), wd = pack2bf(e6, e7);                     \
      asm volatile("v_permlane32_swap_b32 %0, %1" : "+v"(wc), "+v"(wd));       \
      pa[KC] = frag_from_words(wa, wc, wb, wd);                                \
    }
    GROUP(0, st0, 0)
    GROUP(1, st0, 8)
    GROUP(2, st1, 0)
    GROUP(3, st1, 8)
#undef GROUP
    lreg += psum + __shfl_xor(psum, 32);

#pragma unroll
    for (int kc = 0; kc < 4; ++kc) {
      const int sb = hi * 16 + 32 * kc;
      bf16x8 v0 = ldsr(Vb, q31, sb);
      bf16x8 v1 = ldsr(Vb, 32 + q31, sb);
      __builtin_amdgcn_s_setprio(1);
      oacc0 = mfma32(v0, pa[kc], oacc0);
      oacc1 = mfma32(v1, pa[kc], oacc1);
      __builtin_amdgcn_s_setprio(0);
    }

    asm volatile("s_waitcnt vmcnt(0)" ::: "memory");
    __syncthreads();
    cur ^= 1;
  }
#undef STAGE_KV

  const float inv = 1.0f / lreg;
  const int s_tok = qrow0 + q31;
  bf16_t* obase = Ob + (size_t)(b * 1024 + s_tok) * 1024 + h * 64;
#pragma unroll
  for (int i = 0; i < 8; ++i) {
    const int dbase = ((2 * i) & 3) + 8 * ((2 * i) >> 2) + 4 * hi;
    *(unsigned*)(obase + dbase) =
        pack2bf(oacc0[2 * i] * inv, oacc0[2 * i + 1] * inv);
    *(unsigned*)(obase + 32 + dbase) =
        pack2bf(oacc1[2 * i] * inv, oacc1[2 * i + 1] * inv);
  }
}

// ---------------- launch ----------------

extern "C" void kernel_launch(void* const* d_in, const int* in_sizes, int n_in,
                              void* d_out, int out_size, void* d_ws, size_t ws_size,
                              hipStream_t stream) {
  const float* x     = (const float*)d_in[0];
  const float* Wqkv  = (const float*)d_in[1];
  const float* bqkv  = (const float*)d_in[2];
  const float* Wproj = (const float*)d_in[3];
  const float* bproj = (const float*)d_in[4];
  float* out = (float*)d_out;
  char* ws = (char*)d_ws;

  bf16_t* Xb  = (bf16_t*)(ws + OFF_XB);
  bf16_t* Wqt = (bf16_t*)(ws + OFF_WQKVT);
  bf16_t* Wpt = (bf16_t*)(ws + OFF_WPROJT);
  bf16_t* Qh  = (bf16_t*)(ws + OFF_Q);
  bf16_t* Kh  = (bf16_t*)(ws + OFF_K);
  bf16_t* Vt  = (bf16_t*)(ws + OFF_V);
  bf16_t* Ob  = (bf16_t*)(ws + OFF_O);  // aliases Xb (dead after gemm_qkv)

  prologue_kernel<<<8192, 256, 0, stream>>>(x, Xb, Wqkv, Wqt, Wproj, Wpt);
  gemm_qkv<<<1536, 256, 0, stream>>>(Xb, Wqt, bqkv, Qh, Kh, Vt);   // 8 XCD x 8 mt x 24 nt
  attn_kernel<<<1024, 256, 0, stream>>>(Qh, Kh, Vt, Ob);
  gemm_out<<<512, 256, 0, stream>>>(Ob, Wpt, bproj, out);          // 8 XCD x 8 mt x 8 nt
}

// Round 18
// 147.535 us; speedup vs baseline: 1.1930x; 1.1420x over previous
//
#include <hip/hip_runtime.h>
#include <hip/hip_bf16.h>

typedef __bf16 bf16_t;
typedef __attribute__((ext_vector_type(8))) __bf16 bf16x8;
typedef __attribute__((ext_vector_type(4))) float f32x4;
typedef __attribute__((ext_vector_type(16))) float f32x16;

// dims: B=8 S=1024 D=1024 H=16 hd=64
#define QSCALE 0.18033688011112042f   // (1/sqrt(64)) * log2(e)
#define RESCALE_THR 11.5f             // defer-max threshold in log2 units (~8 nats)

// ws layout (bytes). Ob aliases Xb (Xb dead after gemm_qkv).
#define OFF_XB      ((size_t)0)                       // bf16 [8192][1024]  16.78MB
#define OFF_WQKVT   ((size_t)16777216)                // bf16 [3072][1024]   6.29MB
#define OFF_WPROJT  ((size_t)(16777216 + 6291456))    // bf16 [1024][1024]   2.10MB
#define OFF_Q       ((size_t)(16777216 + 6291456 + 2097152)) // bf16 [128][1024][64]
#define OFF_K       (OFF_Q + (size_t)16777216)
#define OFF_V       (OFF_K + (size_t)16777216)        // transposed: [128][64][1024]
#define OFF_O       OFF_XB                            // bf16 [8192][1024] (alias)

typedef const __attribute__((address_space(1))) void* as1cv;
typedef __attribute__((address_space(3))) void* as3v;

__device__ __forceinline__ void load_lds16(const void* g, void* l) {
  __builtin_amdgcn_global_load_lds((as1cv)g, (as3v)l, 16, 0, 0);
}

__device__ __forceinline__ f32x4 mfma16(bf16x8 a, bf16x8 b, f32x4 c) {
  return __builtin_amdgcn_mfma_f32_16x16x32_bf16(a, b, c, 0, 0, 0);
}
__device__ __forceinline__ f32x16 mfma32(bf16x8 a, bf16x8 b, f32x16 c) {
  return __builtin_amdgcn_mfma_f32_32x32x16_bf16(a, b, c, 0, 0, 0);
}

__device__ __forceinline__ float fexp2(float x) { return __builtin_amdgcn_exp2f(x); }

// pack two f32 -> one u32 of two bf16 (compiler fuses to v_cvt_pk_bf16_f32; m240)
__device__ __forceinline__ unsigned pack2bf(float a, float b) {
  union { bf16_t h[2]; unsigned u; } x;
  x.h[0] = (bf16_t)a; x.h[1] = (bf16_t)b;
  return x.u;
}

__device__ __forceinline__ bf16x8 frag_from_words(unsigned w0, unsigned w1,
                                                  unsigned w2, unsigned w3) {
  union { unsigned u[4]; bf16x8 v; } x;
  x.u[0] = w0; x.u[1] = w1; x.u[2] = w2; x.u[3] = w3;
  return x.v;
}

// swizzled LDS read: 16B at (row, slotbyte) with XOR-(row&7) slot swizzle
__device__ __forceinline__ bf16x8 ldsr(const bf16_t* lds, int row, int slotbyte) {
  return *(const bf16x8*)((const char*)lds + row * 128 +
                          (slotbyte ^ ((row & 7) << 4)));
}

// ---------------- merged prologue: x->bf16 copy + both weight transposes ----------------
// blocks [0,4096): cvt of x (8 bf16/thread). blocks [4096,8192): 32x32 transpose
// tiles; tx<96 of each y-row -> Wqkv (cols 3072), else Wproj (cols 1024).
__global__ __launch_bounds__(256) void prologue_kernel(
    const float* __restrict__ x, bf16_t* __restrict__ Xb,
    const float* __restrict__ W1, bf16_t* __restrict__ Wt1,
    const float* __restrict__ W2, bf16_t* __restrict__ Wt2) {
  const int bid = blockIdx.x;
  if (bid < 4096) {
    const int i = bid * 256 + threadIdx.x;          // < 1048576
    const float4* p = (const float4*)x + (size_t)i * 2;
    float4 a = p[0], b = p[1];
    bf16x8 o;
    o[0] = (bf16_t)a.x; o[1] = (bf16_t)a.y; o[2] = (bf16_t)a.z; o[3] = (bf16_t)a.w;
    o[4] = (bf16_t)b.x; o[5] = (bf16_t)b.y; o[6] = (bf16_t)b.z; o[7] = (bf16_t)b.w;
    ((bf16x8*)Xb)[i] = o;
    return;
  }
  __shared__ float t[32][33];
  const int bx = (bid - 4096) & 127;                // 0..127 column-tile
  const int by = (bid - 4096) >> 7;                 // 0..31  row-tile
  const float* W;  bf16_t* Wt;  int cols, c0;
  if (bx < 96) { W = W1; Wt = Wt1; cols = 3072; c0 = bx * 32; }
  else         { W = W2; Wt = Wt2; cols = 1024; c0 = (bx - 96) * 32; }
  const int r0 = by * 32;
  const int tx = threadIdx.x & 31, ty = threadIdx.x >> 5;
  for (int rr = ty; rr < 32; rr += 8)
    t[rr][tx] = W[(size_t)(r0 + rr) * cols + c0 + tx];
  __syncthreads();
  for (int rr = ty; rr < 32; rr += 8)
    Wt[(size_t)(c0 + rr) * 1024 + r0 + tx] = (bf16_t)t[tx][rr];
}

// ---------------- GEMM mainloop (128x128 tile, BK=64, K=1024) ----------------
// R5/R11 structure + SAME-BUFFER prefetch overlap (R14 win: 105->88 us): after
// the fragment ds_reads complete (lgkm0 + barrier), the LDS tile is dead
// (frags in registers), so the NEXT step's global_load_lds go into the same
// buffer and their latency is covered by this step's 32-MFMA cluster — with
// zero extra LDS (occupancy preserved; why R6/R7's dbuf variants lost, and
// why R16's 2-wave variant lost: every trade that pays with occupancy loses).
// Race ledger: barrier#2 preceded by every wave's lgkmcnt(0) -> all reads done
// before any stage data lands; next iter's vmcnt(0)+barrier#1 -> all stages
// landed before reads. sched_barrier(0) pins MFMA between stage-issue & vmcnt.

__device__ __forceinline__ void gemm_mainloop_1024(
    const bf16_t* __restrict__ A, const bf16_t* __restrict__ Bt,
    int m0, int n0, bf16_t* Alds, bf16_t* Blds, f32x4 acc[4][4]) {
  const int tid = threadIdx.x;
  const int w = tid >> 6, lane = tid & 63;
  const int wr = w >> 1, wc = w & 1;
  const int lr = lane & 15, lg = lane >> 4;
#pragma unroll
  for (int m = 0; m < 4; ++m)
#pragma unroll
    for (int n = 0; n < 4; ++n)
      acc[m][n] = f32x4{0.f, 0.f, 0.f, 0.f};

  const int crow = lane >> 3;                    // 0..7 row within 8-row chunk
  const int cels = (((lane & 7) ^ crow) * 8);    // pre-swizzled source slot
  const int rx = (lr & 7) << 4;                  // fragment-read XOR key

#define STAGE_AB(kt_)                                                            \
  do {                                                                           \
    _Pragma("unroll")                                                            \
    for (int it = 0; it < 4; ++it) {                                             \
      const int c = it * 4 + w;                /* chunk 0..15, uniform/wave */   \
      const int rA = c * 8 + crow;             /* tile row 0..127 */             \
      load_lds16(A + (size_t)(m0 + rA) * 1024 + (kt_) * 64 + cels,               \
                 (char*)Alds + c * 1024);                                        \
      load_lds16(Bt + (size_t)(n0 + rA) * 1024 + (kt_) * 64 + cels,              \
                 (char*)Blds + c * 1024);                                        \
    }                                                                            \
  } while (0)

  STAGE_AB(0);

  for (int kt = 0; kt < 16; ++kt) {
    asm volatile("s_waitcnt vmcnt(0)" ::: "memory");   // my stage landed
    asm volatile("s_barrier" ::: "memory");            // everyone's landed

    bf16x8 af[4][2], bfr[4][2];
#pragma unroll
    for (int m = 0; m < 4; ++m)
#pragma unroll
      for (int kk = 0; kk < 2; ++kk)
        af[m][kk] = *(const bf16x8*)((const char*)Alds + (wr * 64 + m * 16 + lr) * 128 +
                                     ((kk * 64 + lg * 16) ^ rx));
#pragma unroll
    for (int n = 0; n < 4; ++n)
#pragma unroll
      for (int kk = 0; kk < 2; ++kk)
        bfr[n][kk] = *(const bf16x8*)((const char*)Blds + (wc * 64 + n * 16 + lr) * 128 +
                                      ((kk * 64 + lg * 16) ^ rx));
    asm volatile("s_waitcnt lgkmcnt(0)" ::: "memory"); // my reads complete
    __builtin_amdgcn_sched_barrier(0);
    asm volatile("s_barrier" ::: "memory");            // all reads done: LDS dead

    if (kt + 1 < 16) STAGE_AB(kt + 1);                 // prefetch into SAME buffer

    __builtin_amdgcn_s_setprio(1);
#pragma unroll
    for (int kk = 0; kk < 2; ++kk)
#pragma unroll
      for (int m = 0; m < 4; ++m)
#pragma unroll
        for (int n = 0; n < 4; ++n)
          acc[m][n] = mfma16(af[m][kk], bfr[n][kk], acc[m][n]);
    __builtin_amdgcn_s_setprio(0);
    __builtin_amdgcn_sched_barrier(0);                 // MFMA stays before vmcnt
  }
#undef STAGE_AB
}

// XCD-chunked remap (T1): hardware assigns XCD = bid % 8; give XCD r the
// contiguous m-tile range [r*MT_PER, (r+1)*MT_PER), nt-outer/mt-inner, so each
// XCD's A panels (MT_PER x 256 KB = 2 MB) stay L2-resident across the n sweep
// and the 8 concurrent mt-blocks share one B panel. Bijective: grid = 8*MT_PER*NT.
__device__ __forceinline__ void xcd_remap(int bid, int MT_PER, int* mt, int* nt) {
  const int r = bid & 7, q = bid >> 3;
  *mt = r * MT_PER + (q & (MT_PER - 1));
  *nt = q / MT_PER;
}

// ---------------- GEMM1: X @ Wqkv^T -> scatter Q(scaled)/K/V(transposed) bf16 ----------------

__global__ __launch_bounds__(256) void gemm_qkv(
    const bf16_t* __restrict__ A, const bf16_t* __restrict__ Bt,
    const float* __restrict__ bias,
    bf16_t* __restrict__ Qh, bf16_t* __restrict__ Kh, bf16_t* __restrict__ Vt) {
  __shared__ alignas(128) bf16_t Alds[128 * 64];
  __shared__ alignas(128) bf16_t Blds[128 * 64];
  int mt, nt;
  xcd_remap(blockIdx.x, 8, &mt, &nt);       // 64 m-tiles, 24 n-tiles
  const int m0 = mt * 128, n0 = nt * 128;
  f32x4 acc[4][4];
  gemm_mainloop_1024(A, Bt, m0, n0, Alds, Blds, acc);

  const int tid = threadIdx.x, w = tid >> 6, lane = tid & 63;
  const int wr = w >> 1, wc = w & 1, lr = lane & 15, lg = lane >> 4;
  const int section = n0 >> 10;  // 0=Q 1=K 2=V (uniform per block)
#pragma unroll
  for (int n = 0; n < 4; ++n) {
    const int c = n0 + wc * 64 + n * 16 + lr;   // global col in [0,3072)
    const float bi = bias[c];
    const int d1024 = c & 1023;
    const int h = d1024 >> 6, d = d1024 & 63;
#pragma unroll
    for (int m = 0; m < 4; ++m) {
      const int r0 = m0 + wr * 64 + m * 16 + lg * 4;     // 4-aligned token base
      if (section == 2) {
        // V: the 4 j-values are CONSECUTIVE s for fixed d -> one 8B store
        // (cuts epilogue store count 4x for V blocks; r0..r0+3 share b since
        //  r0 % 4 == 0; byte addr 8-aligned)
        const int b = r0 >> 10, s = r0 & 1023;
        const size_t hb = ((size_t)(b * 16 + h)) << 16;
        uint2 pk;
        pk.x = pack2bf(acc[m][n][0] + bi, acc[m][n][1] + bi);
        pk.y = pack2bf(acc[m][n][2] + bi, acc[m][n][3] + bi);
        *(uint2*)(Vt + hb + (size_t)d * 1024 + s) = pk;
      } else {
#pragma unroll
        for (int j = 0; j < 4; ++j) {
          const int r = r0 + j;
          const int b = r >> 10, s = r & 1023;
          const size_t hb = ((size_t)(b * 16 + h)) << 16;
          const float v = acc[m][n][j] + bi;
          if (section == 0) Qh[hb + (size_t)s * 64 + d] = (bf16_t)(v * QSCALE);
          else              Kh[hb + (size_t)s * 64 + d] = (bf16_t)v;
        }
      }
    }
  }
}

// ---------------- GEMM2: O @ Wproj^T + b -> fp32 out ----------------

__global__ __launch_bounds__(256) void gemm_out(
    const bf16_t* __restrict__ A, const bf16_t* __restrict__ Bt,
    const float* __restrict__ bias, float* __restrict__ out) {
  __shared__ alignas(128) bf16_t Alds[128 * 64];
  __shared__ alignas(128) bf16_t Blds[128 * 64];
  int mt, nt;
  xcd_remap(blockIdx.x, 8, &mt, &nt);       // 64 m-tiles, 8 n-tiles
  const int m0 = mt * 128, n0 = nt * 128;
  f32x4 acc[4][4];
  gemm_mainloop_1024(A, Bt, m0, n0, Alds, Blds, acc);

  const int tid = threadIdx.x, w = tid >> 6, lane = tid & 63;
  const int wr = w >> 1, wc = w & 1, lr = lane & 15, lg = lane >> 4;
#pragma unroll
  for (int n = 0; n < 4; ++n) {
    const int c = n0 + wc * 64 + n * 16 + lr;
    const float bi = bias[c];
#pragma unroll
    for (int m = 0; m < 4; ++m)
#pragma unroll
      for (int j = 0; j < 4; ++j) {
        const int r = m0 + wr * 64 + m * 16 + lg * 4 + j;
        out[(size_t)r * 1024 + c] = acc[m][n][j] + bi;
      }
  }
}

// ---------------- flash attention, swapped-operand (m214/T12 structure) ----------------
// 4 waves x 32 q-rows. KVBLK=64, dbuf LDS. QK^T computed as St = K·Q^T so each
// lane owns one q-row (col = lane&31); softmax is in-register (tree + 1 shfl_xor(32)).
// P -> PV B-frags via pack2bf + v_permlane32_swap (no P LDS round-trip).
// PV computed as O^T = V^T·P^T so rescale corr is a per-lane scalar.

__global__ __launch_bounds__(256, 4) void attn_kernel(
    const bf16_t* __restrict__ Qh, const bf16_t* __restrict__ Kh,
    const bf16_t* __restrict__ Vt, bf16_t* __restrict__ Ob) {
  __shared__ alignas(128) bf16_t Klds[2][64 * 64];  // [kv][d], XOR-swizzled slots
  __shared__ alignas(128) bf16_t Vlds[2][64 * 64];  // [d][kv], XOR-swizzled slots

  // XCD-aware remap: all 8 q-tiles of one head land on one XCD (T1)
  const int x = blockIdx.x;                // 0..1023
  const int bh = ((x & 7) << 4) | (x >> 6);
  const int qt = (x >> 3) & 7;
  const int b = bh >> 4, h = bh & 15;
  const int tid = threadIdx.x, w = tid >> 6, lane = tid & 63;
  const int q31 = lane & 31, hi = lane >> 5;
  const size_t base = (size_t)bh << 16;    // 65536 elements per head

  const int qrow0 = qt * 128 + w * 32;

  // Q fragments (B-operand of swapped QK^T)
  bf16x8 qf[4];
#pragma unroll
  for (int c = 0; c < 4; ++c)
    qf[c] = *(const bf16x8*)(Qh + base + (size_t)(qrow0 + q31) * 64 + hi * 8 + 16 * c);

  f32x16 oacc0, oacc1;
#pragma unroll
  for (int r = 0; r < 16; ++r) { oacc0[r] = 0.f; oacc1[r] = 0.f; }
  float mreg = -1e30f, lreg = 0.f;

  const int srow = lane >> 3;
  const int sslot = (((lane & 7) ^ srow) << 3);

#define STAGE_KV(bsel, kt_)                                                        \
  do {                                                                             \
    _Pragma("unroll")                                                              \
    for (int it = 0; it < 2; ++it) {                                               \
      const int c = it * 4 + w;                                                    \
      const int r = c * 8 + srow;                                                  \
      load_lds16(Kh + base + (size_t)((kt_) * 64 + r) * 64 + sslot,                \
                 (char*)&Klds[bsel][0] + c * 1024);                                \
      load_lds16(Vt + base + (size_t)r * 1024 + (kt_) * 64 + sslot,                \
                 (char*)&Vlds[bsel][0] + c * 1024);                                \
    }                                                                              \
  } while (0)

  STAGE_KV(0, 0);
  asm volatile("s_waitcnt vmcnt(0)" ::: "memory");
  __syncthreads();
  int cur = 0;

  for (int kt = 0; kt < 16; ++kt) {
    if (kt + 1 < 16) STAGE_KV(cur ^ 1, kt + 1);

    const bf16_t* Kb = &Klds[cur][0];
    const bf16_t* Vb = &Vlds[cur][0];

    f32x16 st0, st1;
#pragma unroll
    for (int r = 0; r < 16; ++r) { st0[r] = 0.f; st1[r] = 0.f; }
#pragma unroll
    for (int c = 0; c < 4; ++c) {
      const int sb = hi * 16 + 32 * c;
      bf16x8 k0 = ldsr(Kb, q31, sb);
      bf16x8 k1 = ldsr(Kb, 32 + q31, sb);
      __builtin_amdgcn_s_setprio(1);
      st0 = mfma32(k0, qf[c], st0);
      st1 = mfma32(k1, qf[c], st1);
      __builtin_amdgcn_s_setprio(0);
    }

    float mx[8];
#pragma unroll
    for (int r = 0; r < 8; ++r)
      mx[r] = fmaxf(fmaxf(st0[r], st0[r + 8]), fmaxf(st1[r], st1[r + 8]));
#pragma unroll
    for (int r = 0; r < 4; ++r) mx[r] = fmaxf(mx[r], mx[r + 4]);
    float tm = fmaxf(fmaxf(mx[0], mx[1]), fmaxf(mx[2], mx[3]));
    tm = fmaxf(tm, __shfl_xor(tm, 32));

    if (!__all(tm - mreg <= RESCALE_THR)) {
      const float mnew = fmaxf(mreg, tm);
      const float corr = fexp2(mreg - mnew);
      lreg *= corr;
#pragma unroll
      for (int r = 0; r < 16; ++r) { oacc0[r] *= corr; oacc1[r] *= corr; }
      mreg = mnew;
    }

    bf16x8 pa[4];
    float psum = 0.f;
#define GROUP(KC, STV, BASE)                                                   \
    {                                                                          \
      const float e0 = fexp2(STV[BASE + 0] - mreg);                            \
      const float e1 = fexp2(STV[BASE + 1] - mreg);                            \
      const float e2 = fexp2(STV[BASE + 2] - mreg);                            \
      const float e3 = fexp2(STV[BASE + 3] - mreg);                            \
      const float e4 = fexp2(STV[BASE + 4] - mreg);                            \
      const float e5 = fexp2(STV[BASE + 5] - mreg);                            \
      const float e6 = fexp2(STV[BASE + 6] - mreg);                            \
      const float e7 = fexp2(STV[BASE + 7] - mreg);                            \
      psum += ((e0 + e1) + (e2 + e3)) + ((e4 + e5) + (e6 + e7));               \
      unsigned wa = pack2bf(e0, e1), wb = pack2bf(e4, e5);                     \
      asm volatile("v_permlane32_swap_b32 %0, %1" : "+v"(wa), "+v"(wb));       \
      unsigned wc = pack2bf(e2, e3), wd = pack2bf(e6, e7);                     \
      asm volatile("v_permlane32_swap_b32 %0, %1" : "+v"(wc), "+v"(wd));       \
      pa[KC] = frag_from_words(wa, wc, wb, wd);                                \
    }
    GROUP(0, st0, 0)
    GROUP(1, st0, 8)
    GROUP(2, st1, 0)
    GROUP(3, st1, 8)
#undef GROUP
    lreg += psum + __shfl_xor(psum, 32);

#pragma unroll
    for (int kc = 0; kc < 4; ++kc) {
      const int sb = hi * 16 + 32 * kc;
      bf16x8 v0 = ldsr(Vb, q31, sb);
      bf16x8 v1 = ldsr(Vb, 32 + q31, sb);
      __builtin_amdgcn_s_setprio(1);
      oacc0 = mfma32(v0, pa[kc], oacc0);
      oacc1 = mfma32(v1, pa[kc], oacc1);
      __builtin_amdgcn_s_setprio(0);
    }

    asm volatile("s_waitcnt vmcnt(0)" ::: "memory");
    __syncthreads();
    cur ^= 1;
  }
#undef STAGE_KV

  const float inv = 1.0f / lreg;
  const int s_tok = qrow0 + q31;
  bf16_t* obase = Ob + (size_t)(b * 1024 + s_tok) * 1024 + h * 64;
#pragma unroll
  for (int i = 0; i < 8; ++i) {
    const int dbase = ((2 * i) & 3) + 8 * ((2 * i) >> 2) + 4 * hi;
    *(unsigned*)(obase + dbase) =
        pack2bf(oacc0[2 * i] * inv, oacc0[2 * i + 1] * inv);
    *(unsigned*)(obase + 32 + dbase) =
        pack2bf(oacc1[2 * i] * inv, oacc1[2 * i + 1] * inv);
  }
}

// ---------------- launch ----------------

extern "C" void kernel_launch(void* const* d_in, const int* in_sizes, int n_in,
                              void* d_out, int out_size, void* d_ws, size_t ws_size,
                              hipStream_t stream) {
  const float* x     = (const float*)d_in[0];
  const float* Wqkv  = (const float*)d_in[1];
  const float* bqkv  = (const float*)d_in[2];
  const float* Wproj = (const float*)d_in[3];
  const float* bproj = (const float*)d_in[4];
  float* out = (float*)d_out;
  char* ws = (char*)d_ws;

  bf16_t* Xb  = (bf16_t*)(ws + OFF_XB);
  bf16_t* Wqt = (bf16_t*)(ws + OFF_WQKVT);
  bf16_t* Wpt = (bf16_t*)(ws + OFF_WPROJT);
  bf16_t* Qh  = (bf16_t*)(ws + OFF_Q);
  bf16_t* Kh  = (bf16_t*)(ws + OFF_K);
  bf16_t* Vt  = (bf16_t*)(ws + OFF_V);
  bf16_t* Ob  = (bf16_t*)(ws + OFF_O);  // aliases Xb (dead after gemm_qkv)

  prologue_kernel<<<8192, 256, 0, stream>>>(x, Xb, Wqkv, Wqt, Wproj, Wpt);
  gemm_qkv<<<1536, 256, 0, stream>>>(Xb, Wqt, bqkv, Qh, Kh, Vt);   // 8 XCD x 8 mt x 24 nt
  attn_kernel<<<1024, 256, 0, stream>>>(Qh, Kh, Vt, Ob);
  gemm_out<<<512, 256, 0, stream>>>(Ob, Wpt, bproj, out);          // 8 XCD x 8 mt x 8 nt
}